// Round 6
// baseline (5973.914 us; speedup 1.0000x reference)
//
#include <hip/hip_runtime.h>
#include <math.h>

constexpr int Bb  = 64;
constexpr int Tt  = 2048;
constexpr int INN = 128;
constexpr int HH  = 256;
constexpr int ROWS = Bb * Tt;   // 131072

typedef __attribute__((ext_vector_type(8))) short bf16x8;
typedef __attribute__((ext_vector_type(4))) float f32x4;

__device__ __forceinline__ unsigned short f2bf(float f) {
    unsigned int u = __float_as_uint(f);
    unsigned int r = u + 0x7FFFu + ((u >> 16) & 1u);   // RNE
    return (unsigned short)(r >> 16);
}

// ---------------------------------------------------------------------------
// GEMM: out[row][j] = sum_k in[row][k] * W[j][k] + bias1[j] + bias2[j]
// (unchanged from R3 — fp32 VALU, ~150 us each; not this round's bottleneck)
// ---------------------------------------------------------------------------
template <int K>
__global__ __launch_bounds__(256) void ih_gemm(const float* in, const float* W,
                                               const float* bias1, const float* bias2,
                                               float* out)
{
    __shared__ float a_lds[16][68];
    __shared__ float b_lds[16][264];

    const int tid = threadIdx.x;
    const int tx  = tid & 31;
    const int ty  = tid >> 5;
    const int row0 = blockIdx.x * 64;

    float acc[8][8];
#pragma unroll
    for (int r = 0; r < 8; ++r)
#pragma unroll
        for (int c = 0; c < 8; ++c) acc[r][c] = 0.f;

    for (int k0 = 0; k0 < K; k0 += 16) {
#pragma unroll
        for (int i = 0; i < 4; ++i) {
            int e = i * 256 + tid;
            int r = e >> 4, kk = e & 15;
            a_lds[kk][r] = in[(row0 + r) * K + k0 + kk];
        }
#pragma unroll
        for (int i = 0; i < 16; ++i) {
            int e = i * 256 + tid;
            int j = e >> 4, kk = e & 15;
            b_lds[kk][j] = W[j * K + k0 + kk];
        }
        __syncthreads();

#pragma unroll
        for (int kk = 0; kk < 16; ++kk) {
            float4 a0 = *(const float4*)&a_lds[kk][ty * 8];
            float4 a1 = *(const float4*)&a_lds[kk][ty * 8 + 4];
            float4 b0 = *(const float4*)&b_lds[kk][tx * 8];
            float4 b1 = *(const float4*)&b_lds[kk][tx * 8 + 4];
            float av[8] = {a0.x, a0.y, a0.z, a0.w, a1.x, a1.y, a1.z, a1.w};
            float bv[8] = {b0.x, b0.y, b0.z, b0.w, b1.x, b1.y, b1.z, b1.w};
#pragma unroll
            for (int r = 0; r < 8; ++r)
#pragma unroll
                for (int c = 0; c < 8; ++c)
                    acc[r][c] += av[r] * bv[c];
        }
        __syncthreads();
    }

    float bsum[8];
#pragma unroll
    for (int c = 0; c < 8; ++c) {
        int j = tx * 8 + c;
        bsum[c] = bias1[j] + bias2[j];
    }
#pragma unroll
    for (int r = 0; r < 8; ++r) {
        int row = row0 + ty * 8 + r;
        float4 o0 = make_float4(acc[r][0] + bsum[0], acc[r][1] + bsum[1],
                                acc[r][2] + bsum[2], acc[r][3] + bsum[3]);
        float4 o1 = make_float4(acc[r][4] + bsum[4], acc[r][5] + bsum[5],
                                acc[r][6] + bsum[6], acc[r][7] + bsum[7]);
        *(float4*)&out[row * HH + tx * 8]     = o0;
        *(float4*)&out[row * HH + tx * 8 + 4] = o1;
    }
}

// ---------------------------------------------------------------------------
// MFMA recurrence. 4 WGs x 16 batches; 256 thr = 4 waves; wave w owns output
// cols [64w, 64w+64) as 4 tiles of mfma_f32_16x16x32_bf16, K=256 = 8 slices.
//   H_t = tanh(Xp_t + H_{t-1} @ Whh^T)   for 16 batch rows at once.
// - Weights: B-frag[tile][slice], B[n=lane&15][k=quad*8+i] = Whh[j][k],
//   j = 64w+16*tile+(lane&15); fp32->bf16 once at start (128 VGPRs).
// - h crosses steps via LDS bf16, row stride 264 (16B-aligned, bank-skewed),
//   double-buffered -> ONE barrier/step. A-frag: lane reads H[m=lane&15]
//   [k=32s+8*quad .. +8] as one b128.
// - C/D layout: n = lane&15, m = quad*4+reg. Epilogue: +xp, fast tanh,
//   fp32 global store (store_all: layer-1 yes, layer-2 only t=T-1),
//   bf16 ds_write into next buffer.
// - R4 BUG FIXED: xp pointers and LDS h-write base were missing the wave's
//   column offset 64*w (all 4 waves hit cols [0,64): races + zero h tail).
// - ALL inner loops fully unrolled (R2 lesson: partial unroll -> scratch).
// ---------------------------------------------------------------------------
__global__ __launch_bounds__(256, 1) void rnn_recur_mfma(float* xp, const float* Whh,
                                                         int store_all)
{
    constexpr int RS = 264;                    // LDS row stride in bf16 elems
    __shared__ unsigned short hb[2][16 * RS];  // 2 x 8.25 KB

    const int tid = threadIdx.x;
    const int w   = tid >> 6;        // wave -> output cols [64w, 64w+64)
    const int l   = tid & 63;
    const int q   = l >> 4;          // quad
    const int lc  = l & 15;
    const int bg  = blockIdx.x;      // batch group: batches 16bg .. 16bg+15

    // ---- weights -> B-frags (one-time) ----
    bf16x8 bf[4][8];
#pragma unroll
    for (int tau = 0; tau < 4; ++tau) {
        const float* wrow = Whh + (64 * w + 16 * tau + lc) * HH;
#pragma unroll
        for (int s = 0; s < 8; ++s) {
            const float4* wp = (const float4*)(wrow + 32 * s + 8 * q);
            float4 lo = wp[0], hi = wp[1];
            bf16x8 v;
            v[0] = (short)f2bf(lo.x); v[1] = (short)f2bf(lo.y);
            v[2] = (short)f2bf(lo.z); v[3] = (short)f2bf(lo.w);
            v[4] = (short)f2bf(hi.x); v[5] = (short)f2bf(hi.y);
            v[6] = (short)f2bf(hi.z); v[7] = (short)f2bf(hi.w);
            bf[tau][s] = v;
        }
    }

    // ---- zero h buffers ----
    for (int i = tid; i < 2 * 16 * RS; i += 256) ((unsigned short*)hb)[i] = 0;

    // ---- per-lane xp pointers: batch m = 4q+r, col j = 64w + 16tau + lc ----
    float* p[4];
#pragma unroll
    for (int r = 0; r < 4; ++r)
        p[r] = xp + ((size_t)(16 * bg + 4 * q + r) * Tt) * HH + 64 * w + lc;

    float xv[4][4];                  // xv[tau][r] = xp[t][m=4q+r][j=64w+16tau+lc]
#pragma unroll
    for (int tau = 0; tau < 4; ++tau)
#pragma unroll
        for (int r = 0; r < 4; ++r) xv[tau][r] = p[r][16 * tau];

    __syncthreads();

#pragma unroll 1
    for (int t = 0; t < Tt; ++t) {
        const int cb = t & 1, nb = cb ^ 1;

        // prefetch next xp (uniform guard keeps t=T-1 in bounds)
        const int off = (t + 1 < Tt) ? HH : 0;
        float xn[4][4];
#pragma unroll
        for (int r = 0; r < 4; ++r) {
            const float* pr = p[r] + off;
#pragma unroll
            for (int tau = 0; tau < 4; ++tau) xn[tau][r] = pr[16 * tau];
        }

        // A-frags: lane reads H[m=lc][32s+8q .. +8] (b128, 16B-aligned)
        const unsigned short* arow = &hb[cb][lc * RS + 8 * q];
        bf16x8 af[8];
#pragma unroll
        for (int s = 0; s < 8; ++s) af[s] = *(const bf16x8*)(arow + 32 * s);

        // 32 MFMAs: 4 independent acc chains of depth 8
        f32x4 acc[4];
#pragma unroll
        for (int tau = 0; tau < 4; ++tau) acc[tau] = (f32x4){0.f, 0.f, 0.f, 0.f};
#pragma unroll
        for (int s = 0; s < 8; ++s)
#pragma unroll
            for (int tau = 0; tau < 4; ++tau)
                acc[tau] = __builtin_amdgcn_mfma_f32_16x16x32_bf16(
                    af[s], bf[tau][s], acc[tau], 0, 0, 0);

        // epilogue: s = acc + xp; h = tanh(s); commit global fp32 + LDS bf16
        unsigned short* wrowlds = &hb[nb][(4 * q) * RS + 64 * w + lc];
#pragma unroll
        for (int tau = 0; tau < 4; ++tau) {
#pragma unroll
            for (int r = 0; r < 4; ++r) {
                float sv = acc[tau][r] + xv[tau][r];
                float e  = __expf(2.f * sv);
                float hn = 1.f - 2.f * __builtin_amdgcn_rcpf(e + 1.f);
                if (store_all || t == Tt - 1) p[r][16 * tau] = hn;
                wrowlds[r * RS + 16 * tau] = f2bf(hn);
            }
        }
        __syncthreads();             // the ONLY barrier per step

#pragma unroll
        for (int tau = 0; tau < 4; ++tau)
#pragma unroll
            for (int r = 0; r < 4; ++r) xv[tau][r] = xn[tau][r];
#pragma unroll
        for (int r = 0; r < 4; ++r) p[r] += HH;
    }
}

// ---------------------------------------------------------------------------
// FC: out[b] = dot(h2[b][T-1][:], W_fc) + b_fc.  One wave per batch.
// ---------------------------------------------------------------------------
__global__ __launch_bounds__(64) void fc_kernel(const float* h2, const float* Wfc,
                                                const float* bfc, float* out)
{
    const int b = blockIdx.x;
    const int l = threadIdx.x;
    const float* hrow = h2 + ((size_t)b * Tt + (Tt - 1)) * HH;
    float4 hv = *(const float4*)&hrow[4 * l];
    float4 wv = *(const float4*)&Wfc[4 * l];
    float p = hv.x * wv.x + hv.y * wv.y + hv.z * wv.z + hv.w * wv.w;
#pragma unroll
    for (int off = 32; off > 0; off >>= 1) p += __shfl_down(p, off, 64);
    if (l == 0) out[b] = p + bfc[0];
}

// ---------------------------------------------------------------------------
extern "C" void kernel_launch(void* const* d_in, const int* in_sizes, int n_in,
                              void* d_out, int out_size, void* d_ws, size_t ws_size,
                              hipStream_t stream)
{
    const float* x     = (const float*)d_in[0];
    const float* W_ih0 = (const float*)d_in[1];
    const float* W_hh0 = (const float*)d_in[2];
    const float* b_ih0 = (const float*)d_in[3];
    const float* b_hh0 = (const float*)d_in[4];
    const float* W_ih1 = (const float*)d_in[5];
    const float* W_hh1 = (const float*)d_in[6];
    const float* b_ih1 = (const float*)d_in[7];
    const float* b_hh1 = (const float*)d_in[8];
    const float* W_fc  = (const float*)d_in[9];
    const float* b_fc  = (const float*)d_in[10];
    float* ws  = (float*)d_ws;                 // B*T*H floats (128 MiB)
    float* out = (float*)d_out;

    ih_gemm<INN><<<ROWS / 64, 256, 0, stream>>>(x, W_ih0, b_ih0, b_hh0, ws);
    rnn_recur_mfma<<<Bb / 16, 256, 0, stream>>>(ws, W_hh0, 1);
    ih_gemm<HH><<<ROWS / 64, 256, 0, stream>>>(ws, W_ih1, b_ih1, b_hh1, ws);
    rnn_recur_mfma<<<Bb / 16, 256, 0, stream>>>(ws, W_hh1, 0);
    fc_kernel<<<Bb, 64, 0, stream>>>(ws, W_fc, b_fc, out);
}